// Round 10
// baseline (262.695 us; speedup 1.0000x reference)
//
#include <hip/hip_runtime.h>
#include <math.h>

#define B_TOT 4096
#define T_LEN 200
#define C_IN  16
#define HH    112
#define G4    448
#define NB    16      // batches per block (= MFMA M)
#define EPS   1e-5f
#define SBLK  256     // stats kernel blocks
#define STHR  1024    // stats kernel threads (16 waves: latency hiding)

typedef _Float16 half8  __attribute__((ext_vector_type(8)));
typedef float    f32x4  __attribute__((ext_vector_type(4)));

#define L2E 1.4426950408889634f
#define FLUSH_MIN 6.103515625e-05f   // fp16 min normal

// fp16 cast with denormal flush — one-time weight conversion only.
__device__ __forceinline__ _Float16 to16f(float v) {
    _Float16 h = (_Float16)v;
    if (__builtin_fabsf(v) < FLUSH_MIN) h = (_Float16)0.0f;
    return h;
}

// ---------------- Kernel 1: deterministic per-channel partial sums ----------------
// 256 blocks x 1024 threads (16 waves/CU) -> latency hidden, ~10 us.
__global__ __launch_bounds__(STHR) void stats_kernel(const float* __restrict__ x,
                                                     float* __restrict__ ws) {
    __shared__ float sm[16][4][8];
    const int tid = threadIdx.x;
    const float4* __restrict__ x4 = (const float4*)x;
    const int total  = B_TOT * T_LEN * C_IN / 4;
    const int stride = SBLK * STHR;
    const int i0 = blockIdx.x * STHR + tid;

    float s0=0.f,s1=0.f,s2=0.f,s3=0.f;
    float q0=0.f,q1=0.f,q2=0.f,q3=0.f;
    for (int i = i0; i < total; i += stride) {
        float4 v = x4[i];
        s0 += v.x; q0 += v.x*v.x;
        s1 += v.y; q1 += v.y*v.y;
        s2 += v.z; q2 += v.z*v.z;
        s3 += v.w; q3 += v.w*v.w;
    }
    #pragma unroll
    for (int off = 4; off < 64; off <<= 1) {
        s0 += __shfl_xor(s0, off); q0 += __shfl_xor(q0, off);
        s1 += __shfl_xor(s1, off); q1 += __shfl_xor(q1, off);
        s2 += __shfl_xor(s2, off); q2 += __shfl_xor(q2, off);
        s3 += __shfl_xor(s3, off); q3 += __shfl_xor(q3, off);
    }
    const int lane = tid & 63, wave = tid >> 6;
    if (lane < 4) {
        sm[wave][lane][0] = s0; sm[wave][lane][1] = s1;
        sm[wave][lane][2] = s2; sm[wave][lane][3] = s3;
        sm[wave][lane][4] = q0; sm[wave][lane][5] = q1;
        sm[wave][lane][6] = q2; sm[wave][lane][7] = q3;
    }
    __syncthreads();
    if (tid < 32) {
        const int ch = tid & 15, sq = tid >> 4;
        const int grp = ch >> 2, comp = ch & 3;
        float a = 0.f;
        #pragma unroll
        for (int wv = 0; wv < 16; wv++) a += sm[wv][grp][sq * 4 + comp];
        ws[blockIdx.x * 32 + tid] = a;
    }
}

// ---------------- Kernel 2: MFMA LSTM, one barrier/step ----------------
// 256 blocks x 448 threads (7 waves). Wave w owns the FOUR GATE TILES of
// j-tile w. Cell update in-lane, c in registers. v_t = [h;x] in LDS,
// A-fragment order, single fp16 plane. Weights k1-prescaled fp16; first
// MFMA per gate takes persistent cinit (prescaled bias) as C operand.
// Round-10: t-loop unrolled x2 with parity-specialized bodies (p is a
// compile-time constant per copy; even copy has no 'last' branch since
// the last step, 199, is odd). setprio removed (R9: null).
// Converged structure: 112 MFMAs/step = exact tile cover; 40 trans/thread
// = LSTM math minimum (2 instr/activation, poly is not cheaper at quarter
// vs full rate); 1 barrier/step = recurrence sync minimum (no sub-block
// barriers on CDNA4; LDS-spin rejected on scheduler-placement deadlock risk).

#define MFMA_NT(nt) do {                                                             \
    ch[nt] = __builtin_amdgcn_mfma_f32_16x16x32_f16(ah[0], wHI[nt][0], cinit[nt], 0, 0, 0); \
    _Pragma("unroll")                                                                \
    for (int kt = 1; kt < 4; ++kt)                                                   \
        ch[nt] = __builtin_amdgcn_mfma_f32_16x16x32_f16(ah[kt], wHI[nt][kt], ch[nt], 0, 0, 0); \
} while (0)

#define ACT_NT(nt) do {                                                              \
    _Pragma("unroll")                                                                \
    for (int r = 0; r < 4; ++r) {                                                    \
        const float e_  = __builtin_amdgcn_exp2f(ch[nt][r]);                         \
        const float rr_ = __builtin_amdgcn_rcpf(1.f + e_);                           \
        act[nt][r] = ((nt) == 2) ? fmaf(2.f, rr_, -1.f) : rr_;                       \
    }                                                                                \
} while (0)

// One timestep. P: compile-time buffer parity. TNEXT: timestep to prefetch.
// ISLAST: compile-time-foldable in the even copy (always false there).
#define STEP_BODY(P, TNEXT, ISLAST)                                                  \
do {                                                                                 \
    float xv0, xv1, xv2, xv3;                                                        \
    const bool pre = xw && ((TNEXT) < T_LEN);                                        \
    if (pre) {                                                                       \
        const size_t o = xg0 + (size_t)(TNEXT) * C_IN;                               \
        xv0 = x[o];                                                                  \
        xv1 = x[o + 1 * (T_LEN * C_IN)];                                             \
        xv2 = x[o + 2 * (T_LEN * C_IN)];                                             \
        xv3 = x[o + 3 * (T_LEN * C_IN)];                                             \
    }                                                                                \
    half8 ah[4];                                                                     \
    _Pragma("unroll")                                                                \
    for (int kt = 0; kt < 4; ++kt)                                                   \
        ah[kt] = *(const half8*)&vbuf[P][kt][lane][0];                               \
    f32x4 ch[4];                                                                     \
    float act[4][4];                                                                 \
    float thc[4];                                                                    \
    /* g-first: cell+tanh(c) trans chain hides under MFMA_o issue */                 \
    MFMA_NT(2);                                                                      \
    MFMA_NT(0);  ACT_NT(2);                                                          \
    MFMA_NT(1);  ACT_NT(0);                                                          \
    MFMA_NT(3);  ACT_NT(1);                                                          \
    _Pragma("unroll")                                                                \
    for (int r = 0; r < 4; ++r) {                                                    \
        const float cn = fmaf(act[1][r], creg[r], act[0][r] * act[2][r]);            \
        creg[r] = cn;                                                                \
        const float e2 = __builtin_amdgcn_exp2f(cn * (-2.f * L2E));                  \
        thc[r] = fmaf(2.f, __builtin_amdgcn_rcpf(1.f + e2), -1.f);                   \
    }                                                                                \
    ACT_NT(3);                                                                       \
    _Pragma("unroll")                                                                \
    for (int r = 0; r < 4; ++r) {                                                    \
        const float hv = act[3][r] * thc[r];                                         \
        if (!(ISLAST)) vbuf[1 - (P)][kt_h][q * 4 + r + qh16][jh] = (_Float16)hv;     \
        else           hfinal[q * 4 + r][jcol] = hv;                                 \
    }                                                                                \
    if (pre) {                                                                       \
        vbuf[1 - (P)][3][xb4 + 0 + xlo][jx] = (_Float16)xv0;                         \
        vbuf[1 - (P)][3][xb4 + 1 + xlo][jx] = (_Float16)xv1;                         \
        vbuf[1 - (P)][3][xb4 + 2 + xlo][jx] = (_Float16)xv2;                         \
        vbuf[1 - (P)][3][xb4 + 3 + xlo][jx] = (_Float16)xv3;                         \
    }                                                                                \
    __syncthreads();                                                                 \
} while (0)

__global__ __launch_bounds__(448, 2) void lstm_kernel(
    const float* __restrict__ x,
    const float* __restrict__ gamma, const float* __restrict__ beta,
    const float* __restrict__ W_ih,  const float* __restrict__ W_hh,
    const float* __restrict__ b_ih,  const float* __restrict__ b_hh,
    const float* __restrict__ W_fc,  const float* __restrict__ b_fc,
    const float* __restrict__ ws,    float* __restrict__ out)
{
    __shared__ float stats_s[32];
    __shared__ float scale_s[16], shift_s[16];
    __shared__ __align__(16) _Float16 vbuf[2][4][64][8]; // [parity][kt][lane][8]
    __shared__ __align__(16) float hfinal[NB][HH];

    const int u    = threadIdx.x;
    const int lane = u & 63;
    const int wv   = u >> 6;          // wave = j-tile 0..6
    const int nloc = lane & 15;
    const int q    = lane >> 4;       // 0..3
    const int b0   = blockIdx.x * NB;

    // --- BN stats (deterministic fixed-order reduction) ---
    if (u < 32) {
        float a = 0.f;
        for (int blk = 0; blk < SBLK; ++blk) a += ws[blk * 32 + u];
        stats_s[u] = a;
    }
    __syncthreads();
    if (u < 16) {
        const float N = (float)B_TOT * (float)T_LEN;
        const float mean = stats_s[u] / N;
        const float var  = stats_s[16 + u] / N - mean * mean;
        const float sc   = gamma[u] * rsqrtf(var + EPS);
        scale_s[u] = sc;
        shift_s[u] = beta[u] - mean * sc;
    }
    for (int i = u; i < (int)(sizeof(vbuf) / 4); i += G4) ((int*)vbuf)[i] = 0;
    __syncthreads();

    // --- Register-resident weight fragments (one-time, fp16, k1-prescaled) ---
    half8 wHI[4][4];
    f32x4 cinit[4];                   // persistent C operand: k1-prescaled bias
    #pragma unroll
    for (int nt = 0; nt < 4; ++nt) {  // nt == gate index
        const int n = nt * HH + wv * 16 + nloc;
        const float mg = (nt == 2) ? 2.f : 1.f;
        const float k1 = -mg * L2E;
        #pragma unroll
        for (int kt = 0; kt < 4; ++kt) {
            const int kb = kt * 32 + q * 8;    // never straddles k=112
            float wtmp[8];
            if (kb < HH) {
                float4 aa = *(const float4*)&W_hh[n * HH + kb];
                float4 bb = *(const float4*)&W_hh[n * HH + kb + 4];
                wtmp[0]=aa.x; wtmp[1]=aa.y; wtmp[2]=aa.z; wtmp[3]=aa.w;
                wtmp[4]=bb.x; wtmp[5]=bb.y; wtmp[6]=bb.z; wtmp[7]=bb.w;
            } else {
                const int c0 = kb - HH;
                float4 aa = *(const float4*)&W_ih[n * C_IN + c0];
                float4 bb = *(const float4*)&W_ih[n * C_IN + c0 + 4];
                wtmp[0]=aa.x*scale_s[c0+0]; wtmp[1]=aa.y*scale_s[c0+1];
                wtmp[2]=aa.z*scale_s[c0+2]; wtmp[3]=aa.w*scale_s[c0+3];
                wtmp[4]=bb.x*scale_s[c0+4]; wtmp[5]=bb.y*scale_s[c0+5];
                wtmp[6]=bb.z*scale_s[c0+6]; wtmp[7]=bb.w*scale_s[c0+7];
            }
            #pragma unroll
            for (int jj = 0; jj < 8; ++jj) wHI[nt][kt][jj] = to16f(k1 * wtmp[jj]);
        }
        float bb2 = b_ih[n] + b_hh[n];
        #pragma unroll
        for (int c = 0; c < C_IN; ++c) bb2 += W_ih[n * C_IN + c] * shift_s[c];
        const float bp = bb2 * k1;
        cinit[nt] = (f32x4){bp, bp, bp, bp};
    }

    // --- h write-back mapping (A-fragment address for column jcol) ---
    const int jcol = wv * 16 + nloc;          // 0..111
    const int kt_h = jcol >> 5;
    const int jh   = jcol & 7;
    const int qh16 = ((jcol >> 3) & 3) * 16;  // lane' = b + qh16

    // --- x staging: wave 3 only (lone wave on SIMD3), 4 elements/lane ---
    const bool xw  = (wv == 3);
    const int  xc  = lane & 15;
    const int  xb4 = (lane >> 4) * 4;         // base batch for this lane
    const size_t xg0 = (size_t)(b0 + xb4) * (T_LEN * C_IN) + xc;
    const int  xlo = 16 * (((HH + xc) >> 3) & 3);   // A-frag lane group for k=112+xc
    const int  jx  = xc & 7;

    if (xw) {
        #pragma unroll
        for (int ii = 0; ii < 4; ++ii) {
            const float v = x[xg0 + (size_t)ii * (T_LEN * C_IN)];
            vbuf[0][3][xb4 + ii + xlo][jx] = (_Float16)v;
        }
    }
    __syncthreads();

    float creg[4] = {0.f, 0.f, 0.f, 0.f};

    // T_LEN = 200 is even: even substep never writes hfinal (last step = 199).
    for (int step = 0; step < T_LEN; step += 2) {
        STEP_BODY(0, step + 1, false);
        STEP_BODY(1, step + 2, (step + 2 == T_LEN));
    }

    // --- FC head ---
    if (u < NB * 6) {
        const int b = u / 6, o = u - b * 6;
        float a = b_fc[o];
        for (int j = 0; j < HH; ++j) a += hfinal[b][j] * W_fc[o * HH + j];
        out[(size_t)(b0 + b) * 6 + o] = tanhf(a);
    }
}

extern "C" void kernel_launch(void* const* d_in, const int* in_sizes, int n_in,
                              void* d_out, int out_size, void* d_ws, size_t ws_size,
                              hipStream_t stream) {
    const float* x     = (const float*)d_in[0];
    const float* gamma = (const float*)d_in[1];
    const float* beta  = (const float*)d_in[2];
    const float* W_ih  = (const float*)d_in[3];
    const float* W_hh  = (const float*)d_in[4];
    const float* b_ih  = (const float*)d_in[5];
    const float* b_hh  = (const float*)d_in[6];
    const float* W_fc  = (const float*)d_in[7];
    const float* b_fc  = (const float*)d_in[8];
    float* out = (float*)d_out;
    float* ws  = (float*)d_ws;

    stats_kernel<<<SBLK, STHR, 0, stream>>>(x, ws);
    lstm_kernel<<<B_TOT / NB, 448, 0, stream>>>(x, gamma, beta, W_ih, W_hh,
                                                b_ih, b_hh, W_fc, b_fc, ws, out);
}

// Round 11
// 255.530 us; speedup vs baseline: 1.0280x; 1.0280x over previous
//
#include <hip/hip_runtime.h>
#include <math.h>

#define B_TOT 4096
#define T_LEN 200
#define C_IN  16
#define HH    112
#define G4    448
#define NB    16      // batches per block (= MFMA M)
#define EPS   1e-5f
#define SBLK  256     // stats kernel blocks
#define STHR  1024    // stats kernel threads (16 waves: latency hiding)

typedef _Float16 half8  __attribute__((ext_vector_type(8)));
typedef float    f32x4  __attribute__((ext_vector_type(4)));

#define L2E 1.4426950408889634f
#define FLUSH_MIN 6.103515625e-05f   // fp16 min normal

// fp16 cast with denormal flush — one-time weight conversion only.
__device__ __forceinline__ _Float16 to16f(float v) {
    _Float16 h = (_Float16)v;
    if (__builtin_fabsf(v) < FLUSH_MIN) h = (_Float16)0.0f;
    return h;
}

// ---------------- Kernel 1: deterministic per-channel partial sums ----------------
// 256 blocks x 1024 threads (16 waves/CU) -> latency hidden, ~10 us.
__global__ __launch_bounds__(STHR) void stats_kernel(const float* __restrict__ x,
                                                     float* __restrict__ ws) {
    __shared__ float sm[16][4][8];
    const int tid = threadIdx.x;
    const float4* __restrict__ x4 = (const float4*)x;
    const int total  = B_TOT * T_LEN * C_IN / 4;
    const int stride = SBLK * STHR;
    const int i0 = blockIdx.x * STHR + tid;

    float s0=0.f,s1=0.f,s2=0.f,s3=0.f;
    float q0=0.f,q1=0.f,q2=0.f,q3=0.f;
    for (int i = i0; i < total; i += stride) {
        float4 v = x4[i];
        s0 += v.x; q0 += v.x*v.x;
        s1 += v.y; q1 += v.y*v.y;
        s2 += v.z; q2 += v.z*v.z;
        s3 += v.w; q3 += v.w*v.w;
    }
    #pragma unroll
    for (int off = 4; off < 64; off <<= 1) {
        s0 += __shfl_xor(s0, off); q0 += __shfl_xor(q0, off);
        s1 += __shfl_xor(s1, off); q1 += __shfl_xor(q1, off);
        s2 += __shfl_xor(s2, off); q2 += __shfl_xor(q2, off);
        s3 += __shfl_xor(s3, off); q3 += __shfl_xor(q3, off);
    }
    const int lane = tid & 63, wave = tid >> 6;
    if (lane < 4) {
        sm[wave][lane][0] = s0; sm[wave][lane][1] = s1;
        sm[wave][lane][2] = s2; sm[wave][lane][3] = s3;
        sm[wave][lane][4] = q0; sm[wave][lane][5] = q1;
        sm[wave][lane][6] = q2; sm[wave][lane][7] = q3;
    }
    __syncthreads();
    if (tid < 32) {
        const int ch = tid & 15, sq = tid >> 4;
        const int grp = ch >> 2, comp = ch & 3;
        float a = 0.f;
        #pragma unroll
        for (int wv = 0; wv < 16; wv++) a += sm[wv][grp][sq * 4 + comp];
        ws[blockIdx.x * 32 + tid] = a;
    }
}

// ---------------- Kernel 2: MFMA LSTM, one barrier/step ----------------
// 256 blocks x 448 threads (7 waves). Wave w owns the FOUR GATE TILES of
// j-tile w. Cell update in-lane, c in registers. v_t = [h;x] in LDS,
// A-fragment order, single fp16 plane. Weights k1-prescaled fp16; first
// MFMA per gate takes persistent cinit (prescaled bias) as C operand.
// FINAL (round-8 variant, best measured: 179.5 us lstm / 256.5 us total).
// Probed and rejected: 14-wave gate-split (R4 +9%), setprio role-split
// (R9 null), x2 parity-unroll (R10 +10%), extra VALU trims (R8 ~0).
// Structural floor: ~2160 cyc/step = VALU issue ~1080 (half transcendental,
// LSTM math minimum) + matrix pipe 620 (112 MFMAs = exact tile cover) +
// ~460 barrier-correlated head/tail latency (1 barrier/step = recurrence
// sync minimum; no sub-block barriers on CDNA4).

#define MFMA_NT(nt) do {                                                             \
    ch[nt] = __builtin_amdgcn_mfma_f32_16x16x32_f16(ah[0], wHI[nt][0], cinit[nt], 0, 0, 0); \
    _Pragma("unroll")                                                                \
    for (int kt = 1; kt < 4; ++kt)                                                   \
        ch[nt] = __builtin_amdgcn_mfma_f32_16x16x32_f16(ah[kt], wHI[nt][kt], ch[nt], 0, 0, 0); \
} while (0)

#define ACT_NT(nt) do {                                                              \
    _Pragma("unroll")                                                                \
    for (int r = 0; r < 4; ++r) {                                                    \
        const float e_  = __builtin_amdgcn_exp2f(ch[nt][r]);                         \
        const float rr_ = __builtin_amdgcn_rcpf(1.f + e_);                           \
        act[nt][r] = ((nt) == 2) ? fmaf(2.f, rr_, -1.f) : rr_;                       \
    }                                                                                \
} while (0)

__global__ __launch_bounds__(448, 2) void lstm_kernel(
    const float* __restrict__ x,
    const float* __restrict__ gamma, const float* __restrict__ beta,
    const float* __restrict__ W_ih,  const float* __restrict__ W_hh,
    const float* __restrict__ b_ih,  const float* __restrict__ b_hh,
    const float* __restrict__ W_fc,  const float* __restrict__ b_fc,
    const float* __restrict__ ws,    float* __restrict__ out)
{
    __shared__ float stats_s[32];
    __shared__ float scale_s[16], shift_s[16];
    __shared__ __align__(16) _Float16 vbuf[2][4][64][8]; // [parity][kt][lane][8]
    __shared__ __align__(16) float hfinal[NB][HH];

    const int u    = threadIdx.x;
    const int lane = u & 63;
    const int wv   = u >> 6;          // wave = j-tile 0..6
    const int nloc = lane & 15;
    const int q    = lane >> 4;       // 0..3
    const int b0   = blockIdx.x * NB;

    // --- BN stats (deterministic fixed-order reduction) ---
    if (u < 32) {
        float a = 0.f;
        for (int blk = 0; blk < SBLK; ++blk) a += ws[blk * 32 + u];
        stats_s[u] = a;
    }
    __syncthreads();
    if (u < 16) {
        const float N = (float)B_TOT * (float)T_LEN;
        const float mean = stats_s[u] / N;
        const float var  = stats_s[16 + u] / N - mean * mean;
        const float sc   = gamma[u] * rsqrtf(var + EPS);
        scale_s[u] = sc;
        shift_s[u] = beta[u] - mean * sc;
    }
    for (int i = u; i < (int)(sizeof(vbuf) / 4); i += G4) ((int*)vbuf)[i] = 0;
    __syncthreads();

    // --- Register-resident weight fragments (one-time, fp16, k1-prescaled) ---
    half8 wHI[4][4];
    f32x4 cinit[4];                   // persistent C operand: k1-prescaled bias
    #pragma unroll
    for (int nt = 0; nt < 4; ++nt) {  // nt == gate index
        const int n = nt * HH + wv * 16 + nloc;
        const float mg = (nt == 2) ? 2.f : 1.f;
        const float k1 = -mg * L2E;
        #pragma unroll
        for (int kt = 0; kt < 4; ++kt) {
            const int kb = kt * 32 + q * 8;    // never straddles k=112
            float wtmp[8];
            if (kb < HH) {
                float4 aa = *(const float4*)&W_hh[n * HH + kb];
                float4 bb = *(const float4*)&W_hh[n * HH + kb + 4];
                wtmp[0]=aa.x; wtmp[1]=aa.y; wtmp[2]=aa.z; wtmp[3]=aa.w;
                wtmp[4]=bb.x; wtmp[5]=bb.y; wtmp[6]=bb.z; wtmp[7]=bb.w;
            } else {
                const int c0 = kb - HH;
                float4 aa = *(const float4*)&W_ih[n * C_IN + c0];
                float4 bb = *(const float4*)&W_ih[n * C_IN + c0 + 4];
                wtmp[0]=aa.x*scale_s[c0+0]; wtmp[1]=aa.y*scale_s[c0+1];
                wtmp[2]=aa.z*scale_s[c0+2]; wtmp[3]=aa.w*scale_s[c0+3];
                wtmp[4]=bb.x*scale_s[c0+4]; wtmp[5]=bb.y*scale_s[c0+5];
                wtmp[6]=bb.z*scale_s[c0+6]; wtmp[7]=bb.w*scale_s[c0+7];
            }
            #pragma unroll
            for (int jj = 0; jj < 8; ++jj) wHI[nt][kt][jj] = to16f(k1 * wtmp[jj]);
        }
        float bb2 = b_ih[n] + b_hh[n];
        #pragma unroll
        for (int c = 0; c < C_IN; ++c) bb2 += W_ih[n * C_IN + c] * shift_s[c];
        const float bp = bb2 * k1;
        cinit[nt] = (f32x4){bp, bp, bp, bp};
    }

    // --- h write-back mapping (A-fragment address for column jcol) ---
    const int jcol = wv * 16 + nloc;          // 0..111
    const int kt_h = jcol >> 5;
    const int jh   = jcol & 7;
    const int qh16 = ((jcol >> 3) & 3) * 16;  // lane' = b + qh16

    // --- x staging: wave 3 only (lone wave on SIMD3), 4 elements/lane ---
    // lane l: channel c = l&15, batches b = (l>>4)*4 + ii, ii = 0..3
    const bool xw  = (wv == 3);
    const int  xc  = lane & 15;
    const int  xb4 = (lane >> 4) * 4;         // base batch for this lane
    const size_t xg0 = (size_t)(b0 + xb4) * (T_LEN * C_IN) + xc;
    const int  xlo = 16 * (((HH + xc) >> 3) & 3);   // A-frag lane group for k=112+xc
    const int  jx  = xc & 7;

    if (xw) {
        #pragma unroll
        for (int ii = 0; ii < 4; ++ii) {
            const float v = x[xg0 + (size_t)ii * (T_LEN * C_IN)];
            vbuf[0][3][xb4 + ii + xlo][jx] = (_Float16)v;
        }
    }
    __syncthreads();

    float creg[4] = {0.f, 0.f, 0.f, 0.f};

    for (int step = 0; step < T_LEN; ++step) {
        const int p = step & 1;

        // wave-3 x prefetch for t+1 (hidden under this step's compute)
        float xv0, xv1, xv2, xv3;
        if (xw && step + 1 < T_LEN) {
            const size_t o = xg0 + (size_t)(step + 1) * C_IN;
            xv0 = x[o];
            xv1 = x[o + 1 * (T_LEN * C_IN)];
            xv2 = x[o + 2 * (T_LEN * C_IN)];
            xv3 = x[o + 3 * (T_LEN * C_IN)];
        }

        // A-fragments for this step (all 4 k-tiles, single plane)
        half8 ah[4];
        #pragma unroll
        for (int kt = 0; kt < 4; ++kt)
            ah[kt] = *(const half8*)&vbuf[p][kt][lane][0];

        f32x4 ch[4];
        float act[4][4];
        float thc[4];

        // g-first pipeline: ACT_g early so the cell+tanh(c) trans chain
        // (needs i,f,g) hides under MFMA_o's issue window; only ACT_o + h
        // remain as serial tail.
        MFMA_NT(2);              // g
        MFMA_NT(0);  ACT_NT(2);  // i  | act_g
        MFMA_NT(1);  ACT_NT(0);  // f  | act_i
        MFMA_NT(3);  ACT_NT(1);  // o  | act_f
        #pragma unroll
        for (int r = 0; r < 4; ++r) {
            const float cn = fmaf(act[1][r], creg[r], act[0][r] * act[2][r]);
            creg[r] = cn;
            const float e2 = __builtin_amdgcn_exp2f(cn * (-2.f * L2E));
            thc[r] = fmaf(2.f, __builtin_amdgcn_rcpf(1.f + e2), -1.f);
        }
        ACT_NT(3);               // act_o (after MFMA_o drain)

        const bool last = (step + 1 == T_LEN);
        #pragma unroll
        for (int r = 0; r < 4; ++r) {
            const float hv = act[3][r] * thc[r];
            if (!last) {
                vbuf[1 - p][kt_h][q * 4 + r + qh16][jh] = (_Float16)hv;
            } else {
                hfinal[q * 4 + r][jcol] = hv;
            }
        }
        if (xw && step + 1 < T_LEN) {
            vbuf[1 - p][3][xb4 + 0 + xlo][jx] = (_Float16)xv0;
            vbuf[1 - p][3][xb4 + 1 + xlo][jx] = (_Float16)xv1;
            vbuf[1 - p][3][xb4 + 2 + xlo][jx] = (_Float16)xv2;
            vbuf[1 - p][3][xb4 + 3 + xlo][jx] = (_Float16)xv3;
        }
        __syncthreads();
    }

    // --- FC head ---
    if (u < NB * 6) {
        const int b = u / 6, o = u - b * 6;
        float a = b_fc[o];
        for (int j = 0; j < HH; ++j) a += hfinal[b][j] * W_fc[o * HH + j];
        out[(size_t)(b0 + b) * 6 + o] = tanhf(a);
    }
}

extern "C" void kernel_launch(void* const* d_in, const int* in_sizes, int n_in,
                              void* d_out, int out_size, void* d_ws, size_t ws_size,
                              hipStream_t stream) {
    const float* x     = (const float*)d_in[0];
    const float* gamma = (const float*)d_in[1];
    const float* beta  = (const float*)d_in[2];
    const float* W_ih  = (const float*)d_in[3];
    const float* W_hh  = (const float*)d_in[4];
    const float* b_ih  = (const float*)d_in[5];
    const float* b_hh  = (const float*)d_in[6];
    const float* W_fc  = (const float*)d_in[7];
    const float* b_fc  = (const float*)d_in[8];
    float* out = (float*)d_out;
    float* ws  = (float*)d_ws;

    stats_kernel<<<SBLK, STHR, 0, stream>>>(x, ws);
    lstm_kernel<<<B_TOT / NB, 448, 0, stream>>>(x, gamma, beta, W_ih, W_hh,
                                                b_ih, b_hh, W_fc, b_fc, ws, out);
}